// Round 2
// baseline (19517.319 us; speedup 1.0000x reference)
//
#include <hip/hip_runtime.h>
#include <hip/hip_bf16.h>
#include <stdint.h>
#include <math.h>

// Problem dims
constexpr int SEQ  = 4096;
constexpr int DIN  = 1152;
constexpr int HID  = 512;
constexpr int G4H  = 2048;   // 4*HID
constexpr int KTAG = 24;
constexpr float NEGV = -10000.0f;

__device__ __forceinline__ float sigm(float x) { return 1.0f / (1.0f + expf(-x)); }

// =====================================================================
// GEMM: C[SEQ][2048] = A[SEQ][KA] @ W[2048][KA]^T + b     (fp32, 64x64 tile)
// mode 0: A is a plain [SEQ][KA] matrix.
// mode 1: A row t is concat(hf[t+1][0:512], hb[SEQ-t][0:512])  (bidir LSTM output)
// blockIdx.z selects the (Wf,bf,Cf) or (Wb,bb,Cb) problem.
// =====================================================================
__global__ __launch_bounds__(256) void gemm_proj(
    const float* __restrict__ A, const float* __restrict__ hf, const float* __restrict__ hb,
    int KA, int mode,
    const float* __restrict__ Wf, const float* __restrict__ bf, float* __restrict__ Cf,
    const float* __restrict__ Wb, const float* __restrict__ bb, float* __restrict__ Cb)
{
    const float* W    = blockIdx.z ? Wb : Wf;
    const float* bias = blockIdx.z ? bb : bf;
    float*       C    = blockIdx.z ? Cb : Cf;

    __shared__ __align__(16) float As[32][68];   // [k][m], pad 68 to break conflicts, keep 16B align
    __shared__ __align__(16) float Ws[32][68];   // [k][n]

    const int tid  = threadIdx.x;
    const int bm   = blockIdx.x * 64;
    const int bn   = blockIdx.y * 64;
    const int lrow = tid >> 2;          // 0..63
    const int kq   = (tid & 3) * 8;     // 0,8,16,24
    const int tx   = tid & 15, ty = tid >> 4;

    float acc[4][4] = {};

    for (int bk = 0; bk < KA; bk += 32) {
        float4 a0, a1;
        const int arow = bm + lrow;
        const int k0   = bk + kq;
        if (mode == 0) {
            const float* p = A + (size_t)arow * KA + k0;
            a0 = *(const float4*)p;
            a1 = *(const float4*)(p + 4);
        } else {
            const float* p0 = (k0 < 512) ? (hf + (size_t)(arow + 1) * HID + k0)
                                         : (hb + (size_t)(SEQ - arow) * HID + (k0 - 512));
            const int k1 = k0 + 4;
            const float* p1 = (k1 < 512) ? (hf + (size_t)(arow + 1) * HID + k1)
                                         : (hb + (size_t)(SEQ - arow) * HID + (k1 - 512));
            a0 = *(const float4*)p0;
            a1 = *(const float4*)p1;
        }
        const float* q = W + (size_t)(bn + lrow) * KA + k0;
        const float4 w0 = *(const float4*)q;
        const float4 w1 = *(const float4*)(q + 4);

        As[kq+0][lrow] = a0.x; As[kq+1][lrow] = a0.y; As[kq+2][lrow] = a0.z; As[kq+3][lrow] = a0.w;
        As[kq+4][lrow] = a1.x; As[kq+5][lrow] = a1.y; As[kq+6][lrow] = a1.z; As[kq+7][lrow] = a1.w;
        Ws[kq+0][lrow] = w0.x; Ws[kq+1][lrow] = w0.y; Ws[kq+2][lrow] = w0.z; Ws[kq+3][lrow] = w0.w;
        Ws[kq+4][lrow] = w1.x; Ws[kq+5][lrow] = w1.y; Ws[kq+6][lrow] = w1.z; Ws[kq+7][lrow] = w1.w;
        __syncthreads();

        #pragma unroll
        for (int kk = 0; kk < 32; ++kk) {
            const float4 av = *(const float4*)&As[kk][ty * 4];
            const float4 wv = *(const float4*)&Ws[kk][tx * 4];
            acc[0][0] = fmaf(av.x, wv.x, acc[0][0]); acc[0][1] = fmaf(av.x, wv.y, acc[0][1]);
            acc[0][2] = fmaf(av.x, wv.z, acc[0][2]); acc[0][3] = fmaf(av.x, wv.w, acc[0][3]);
            acc[1][0] = fmaf(av.y, wv.x, acc[1][0]); acc[1][1] = fmaf(av.y, wv.y, acc[1][1]);
            acc[1][2] = fmaf(av.y, wv.z, acc[1][2]); acc[1][3] = fmaf(av.y, wv.w, acc[1][3]);
            acc[2][0] = fmaf(av.z, wv.x, acc[2][0]); acc[2][1] = fmaf(av.z, wv.y, acc[2][1]);
            acc[2][2] = fmaf(av.z, wv.z, acc[2][2]); acc[2][3] = fmaf(av.z, wv.w, acc[2][3]);
            acc[3][0] = fmaf(av.w, wv.x, acc[3][0]); acc[3][1] = fmaf(av.w, wv.y, acc[3][1]);
            acc[3][2] = fmaf(av.w, wv.z, acc[3][2]); acc[3][3] = fmaf(av.w, wv.w, acc[3][3]);
        }
        __syncthreads();
    }

    const float4 bv = *(const float4*)&bias[bn + tx * 4];
    #pragma unroll
    for (int im = 0; im < 4; ++im) {
        float4 o;
        o.x = acc[im][0] + bv.x; o.y = acc[im][1] + bv.y;
        o.z = acc[im][2] + bv.z; o.w = acc[im][3] + bv.w;
        *(float4*)&C[(size_t)(bm + ty * 4 + im) * G4H + bn + tx * 4] = o;
    }
}

// =====================================================================
// Persistent bidirectional LSTM layer.
// 128 WGs x 256 threads. WGs [0,64): forward dir, [64,128): backward dir.
// Each WG owns 8 hidden units j' in [8w, 8w+8): the 32 z-rows {g*512 + j'}.
// Weights Whh[row][512] held in VGPRs (64 floats/thread).
// h-state exchanged via hist[s] slots in global memory using NaN-sentinel
// value-spin (relaxed agent-scope atomics, write-through to LLC). hist must
// be pre-filled with 0xFF bytes. No flags, no fences, no ABA (per-step slot).
// =====================================================================
__global__ __launch_bounds__(256) void lstm_layer(
    const float* __restrict__ Pf, const float* __restrict__ Pb,
    const float* __restrict__ Whhf, const float* __restrict__ Whhb,
    const float* __restrict__ h0, const float* __restrict__ c0, int h0base,
    float* __restrict__ histf, float* __restrict__ histb)
{
    const int wg  = blockIdx.x;
    const int dir = wg >> 6;            // 0 fwd, 1 bwd
    const int w   = wg & 63;            // slice id
    const float* P    = dir ? Pb : Pf;
    const float* Whh  = dir ? Whhb : Whhf;
    float* histW      = dir ? histb : histf;

    const int tid  = threadIdx.x;
    const int wave = tid >> 6;
    const int lane = tid & 63;
    const int r    = lane & 31;                    // local row 0..31
    const int cc   = (wave << 1) | (lane >> 5);    // k-chunk 0..7 (64 wide)
    const int gate = r >> 3;
    const int jj8  = (w << 3) | (r & 7);           // hidden index in [0,512)
    const int grow = gate * HID + jj8;             // z row in [0,2048)

    // weights -> registers
    float4 wv[16];
    {
        const float4* wp = (const float4*)(Whh + (size_t)grow * HID + cc * 64);
        #pragma unroll
        for (int i = 0; i < 16; ++i) wv[i] = wp[i];
    }

    // cell state (wave 0, lanes 0..7)
    float c = 0.0f;
    if (wave == 0 && lane < 8) c = c0[(size_t)(h0base + dir) * HID + (w << 3) + lane];

    __shared__ __align__(16) float hs[512];
    __shared__ float part[4][32];

    // initial h
    {
        const float2 h2 = *(const float2*)&h0[(size_t)(h0base + dir) * HID + tid * 2];
        *(float2*)&hs[tid * 2] = h2;
    }
    __syncthreads();

    for (int s = 0; s < SEQ; ++s) {
        const int t = dir ? (SEQ - 1 - s) : s;

        // prefetch input-projection term early (covers its latency with the matvec)
        float zP = 0.0f;
        if (wave == 0) zP = P[(size_t)t * G4H + grow];

        // matvec partial: rows for this lane, k in [cc*64, cc*64+64)
        float acc = 0.0f;
        const float* hbase = &hs[cc * 64];
        #pragma unroll
        for (int i = 0; i < 16; ++i) {
            const float4 h4 = *(const float4*)&hbase[i * 4];
            acc = fmaf(wv[i].x, h4.x, acc);
            acc = fmaf(wv[i].y, h4.y, acc);
            acc = fmaf(wv[i].z, h4.z, acc);
            acc = fmaf(wv[i].w, h4.w, acc);
        }
        acc += __shfl_xor(acc, 32);                // combine the 2 k-chunks of this wave
        if (lane < 32) part[wave][r] = acc;
        __syncthreads();

        if (wave == 0) {
            float z = part[0][r] + part[1][r] + part[2][r] + part[3][r] + zP;
            const int jl = lane & 7;
            const float zi = __shfl(z, jl);
            const float zf = __shfl(z, jl + 8);
            const float zg = __shfl(z, jl + 16);
            const float zo = __shfl(z, jl + 24);
            const float cn = sigm(zf) * c + sigm(zi) * tanhf(zg);
            const float hv = sigm(zo) * tanhf(cn);
            if (lane < 8) {
                c = cn;
                __hip_atomic_store(&histW[(size_t)(s + 1) * HID + (w << 3) + lane], hv,
                                   __ATOMIC_RELAXED, __HIP_MEMORY_SCOPE_AGENT);
            }
        }

        if (s + 1 < SEQ) {
            __syncthreads();   // everyone done with current hs / part
            const uint32_t* src = (const uint32_t*)(histW + (size_t)(s + 1) * HID);
            uint32_t v0, v1;
            do {
                v0 = __hip_atomic_load(&src[tid * 2 + 0], __ATOMIC_RELAXED, __HIP_MEMORY_SCOPE_AGENT);
                v1 = __hip_atomic_load(&src[tid * 2 + 1], __ATOMIC_RELAXED, __HIP_MEMORY_SCOPE_AGENT);
            } while (v0 == 0xFFFFFFFFu || v1 == 0xFFFFFFFFu);
            hs[tid * 2 + 0] = __uint_as_float(v0);
            hs[tid * 2 + 1] = __uint_as_float(v1);
            __syncthreads();
        }
    }
}

// =====================================================================
// feats[t][j] = b_tag[j] + sum_k y1[t][k] * Wtag[j][k], y1 from hist buffers.
// One wave per t-row.
// =====================================================================
__global__ __launch_bounds__(256) void feats_kernel(
    const float* __restrict__ hf, const float* __restrict__ hb,
    const float* __restrict__ Wtag, const float* __restrict__ btag, float* __restrict__ feats)
{
    const int wv = threadIdx.x >> 6, lane = threadIdx.x & 63;
    const int t  = blockIdx.x * 4 + wv;
    const int k0 = lane * 16;
    const float* src = (k0 < 512) ? (hf + (size_t)(t + 1) * HID + k0)
                                  : (hb + (size_t)(SEQ - t) * HID + (k0 - 512));
    const float4 y0 = ((const float4*)src)[0];
    const float4 y1 = ((const float4*)src)[1];
    const float4 y2 = ((const float4*)src)[2];
    const float4 y3 = ((const float4*)src)[3];
    for (int j = 0; j < KTAG; ++j) {
        const float4* wp = (const float4*)&Wtag[(size_t)j * 1024 + k0];
        const float4 w0 = wp[0], w1 = wp[1], w2 = wp[2], w3 = wp[3];
        float p = 0.0f;
        p = fmaf(y0.x, w0.x, p); p = fmaf(y0.y, w0.y, p); p = fmaf(y0.z, w0.z, p); p = fmaf(y0.w, w0.w, p);
        p = fmaf(y1.x, w1.x, p); p = fmaf(y1.y, w1.y, p); p = fmaf(y1.z, w1.z, p); p = fmaf(y1.w, w1.w, p);
        p = fmaf(y2.x, w2.x, p); p = fmaf(y2.y, w2.y, p); p = fmaf(y2.z, w2.z, p); p = fmaf(y2.w, w2.w, p);
        p = fmaf(y3.x, w3.x, p); p = fmaf(y3.y, w3.y, p); p = fmaf(y3.z, w3.z, p); p = fmaf(y3.w, w3.w, p);
        #pragma unroll
        for (int off = 32; off; off >>= 1) p += __shfl_xor(p, off);
        if (lane == 0) feats[(size_t)t * KTAG + j] = p + btag[j];
    }
}

// =====================================================================
// Sequential Viterbi max scan (bit-exact vs reference, no argmax on chain).
// 1 wave. Lane layout: to = lane%24, half = lane/24 covers 12 'from' each.
// fv rows stored to fvstore (slot 0 = init, slot t+1 = fv_t) for bp recompute.
// =====================================================================
__global__ __launch_bounds__(64) void viterbi_scan(
    const float* __restrict__ feats, const float* __restrict__ trans,
    float* __restrict__ fvstore, float* __restrict__ out, int* __restrict__ bestb)
{
    const int lane = threadIdx.x;
    const int to = lane % 24, hh = lane / 24;
    const bool act = hh < 2;
    const int hb = (hh & 1) * 12;

    float tr[12], fvr[12];
    #pragma unroll
    for (int i = 0; i < 12; ++i) tr[i] = act ? trans[to * 24 + hb + i] : -3.0e37f;
    #pragma unroll
    for (int i = 0; i < 12; ++i) fvr[i] = (hb + i == 0) ? 0.0f : NEGV;
    if (lane < 24) fvstore[lane] = (lane == 0) ? 0.0f : NEGV;

    float ftc = (lane < 24) ? feats[lane] : 0.0f;
    const int partner = act ? (to + ((hh ^ 1) * 24)) : lane;
    float fvnew = 0.0f;

    for (int t = 0; t < SEQ; ++t) {
        const float ftn = (lane < 24 && t + 1 < SEQ) ? feats[(size_t)(t + 1) * KTAG + lane] : 0.0f;
        float v0  = fvr[0]  + tr[0],  v1  = fvr[1]  + tr[1];
        float v2  = fvr[2]  + tr[2],  v3  = fvr[3]  + tr[3];
        float v4  = fvr[4]  + tr[4],  v5  = fvr[5]  + tr[5];
        float v6  = fvr[6]  + tr[6],  v7  = fvr[7]  + tr[7];
        float v8  = fvr[8]  + tr[8],  v9  = fvr[9]  + tr[9];
        float v10 = fvr[10] + tr[10], v11 = fvr[11] + tr[11];
        float m = fmaxf(fmaxf(fmaxf(v0, v1), fmaxf(v2, v3)),
                        fmaxf(fmaxf(v4, v5), fmaxf(v6, v7)));
        m = fmaxf(m, fmaxf(fmaxf(v8, v9), fmaxf(v10, v11)));
        m = fmaxf(m, __shfl(m, partner));
        fvnew = m + ftc;                 // valid on lanes < 24
        if (lane < 24) fvstore[(size_t)(t + 1) * KTAG + lane] = fvnew;
        #pragma unroll
        for (int i = 0; i < 12; ++i) fvr[i] = __shfl(fvnew, hb + i);   // re-replicate
        ftc = ftn;
    }

    // terminal
    float val = -3.0e38f; int idx = lane;
    if (lane < 24) {
        val = fvnew + trans[1 * 24 + lane];          // transitions[STOP][from]
        if (lane == 0 || lane == 1) val = NEGV;      // exclude START, STOP
    }
    #pragma unroll
    for (int off = 16; off; off >>= 1) {
        const float ov = __shfl_xor(val, off);
        const int   oi = __shfl_xor(idx, off);
        if (ov > val || (ov == val && oi < idx)) { val = ov; idx = oi; }
    }
    if (lane == 0) { out[0] = val; *bestb = idx; }
}

// =====================================================================
// Recompute backpointers in parallel: bp[t][to] = argmax_from(fv_{t-1}[from]+trans)
// Identical fp32 adds + first-index tie rule -> matches the sequential scan.
// =====================================================================
__global__ __launch_bounds__(256) void bp_kernel(
    const float* __restrict__ fvstore, const float* __restrict__ trans, uint8_t* __restrict__ bp)
{
    const int idx = blockIdx.x * 256 + threadIdx.x;
    const int t = idx / KTAG, to = idx % KTAG;
    const float* fv = fvstore + (size_t)t * KTAG;   // slot t = fv_{t-1}
    const float* tr = trans + to * 24;
    float m = fv[0] + tr[0]; int bi = 0;
    #pragma unroll
    for (int f = 1; f < 24; ++f) {
        const float v = fv[f] + tr[f];
        if (v > m) { m = v; bi = f; }
    }
    bp[idx] = (uint8_t)bi;
}

// =====================================================================
// Parallel backtrace via exact integer map composition over 64-step chunks.
// =====================================================================
__global__ __launch_bounds__(1024) void backtrace_kernel(
    const uint8_t* __restrict__ bp, const int* __restrict__ bestb, float* __restrict__ out)
{
    __shared__ uint8_t E[64][24];
    __shared__ uint8_t tops[64];
    const int tid = threadIdx.x;
    const int wv = tid >> 6, lane = tid & 63;

    // phase 1: chunk maps E_c: top_c -> top_{c-1} (applies bp[64c+63] .. bp[64c])
    for (int ci = 0; ci < 4; ++ci) {
        const int ck = wv * 4 + ci;
        if (lane < 24) {
            int y = lane;
            for (int k = 63; k >= 0; --k) y = bp[(size_t)(ck * 64 + k) * KTAG + y];
            E[ck][lane] = (uint8_t)y;
        }
    }
    __syncthreads();

    // phase 2: serial fold over 64 chunk maps
    if (tid == 0) {
        int topc = *bestb;
        tops[63] = (uint8_t)topc;
        for (int ck = 63; ck >= 1; --ck) { topc = E[ck][topc]; tops[ck - 1] = (uint8_t)topc; }
    }
    __syncthreads();

    // phase 3: fill each chunk
    for (int ci = 0; ci < 4; ++ci) {
        const int ck = wv * 4 + ci;
        if (lane == 0) {
            int y = tops[ck];
            out[1 + ck * 64 + 63] = (float)y;
            for (int tt = ck * 64 + 62; tt >= ck * 64; --tt) {
                y = bp[(size_t)(tt + 1) * KTAG + y];
                out[1 + tt] = (float)y;
            }
        }
    }
}

// =====================================================================
extern "C" void kernel_launch(void* const* d_in, const int* in_sizes, int n_in,
                              void* d_out, int out_size, void* d_ws, size_t ws_size,
                              hipStream_t stream)
{
    (void)in_sizes; (void)n_in; (void)out_size; (void)ws_size;
    // Inputs in setup_inputs() dict INSERTION order: transitions is added
    // LAST (after h0/c0), even though the reference signature lists it earlier.
    const float* X     = (const float*)d_in[0];
    const float* Wih0f = (const float*)d_in[1];
    const float* Whh0f = (const float*)d_in[2];
    const float* b0f   = (const float*)d_in[3];
    const float* Wih0b = (const float*)d_in[4];
    const float* Whh0b = (const float*)d_in[5];
    const float* b0b   = (const float*)d_in[6];
    const float* Wih1f = (const float*)d_in[7];
    const float* Whh1f = (const float*)d_in[8];
    const float* b1f   = (const float*)d_in[9];
    const float* Wih1b = (const float*)d_in[10];
    const float* Whh1b = (const float*)d_in[11];
    const float* b1b   = (const float*)d_in[12];
    const float* Wtag  = (const float*)d_in[13];
    const float* btag  = (const float*)d_in[14];
    const float* h0    = (const float*)d_in[15];
    const float* c0    = (const float*)d_in[16];
    const float* trans = (const float*)d_in[17];
    float* out = (float*)d_out;

    // workspace carve-up (floats)
    float* f   = (float*)d_ws;
    float* Pf  = f;                                   // SEQ*2048
    float* Pb  = Pf  + (size_t)SEQ * G4H;             // SEQ*2048
    float* hf0 = Pb  + (size_t)SEQ * G4H;             // (SEQ+1)*512 each
    float* hb0 = hf0 + (size_t)(SEQ + 1) * HID;
    float* hf1 = hb0 + (size_t)(SEQ + 1) * HID;
    float* hb1 = hf1 + (size_t)(SEQ + 1) * HID;
    float* feats = hb1 + (size_t)(SEQ + 1) * HID;     // SEQ*24
    float* fvst  = feats + (size_t)SEQ * KTAG;        // (SEQ+1)*24
    int*   bestb = (int*)(fvst + (size_t)(SEQ + 1) * KTAG);
    uint8_t* bp  = (uint8_t*)(bestb + 4);             // SEQ*24 bytes

    // NaN-sentinel fill for all 4 hist buffers (sync mechanism for the LSTM)
    hipMemsetAsync(hf0, 0xFF, (size_t)4 * (SEQ + 1) * HID * sizeof(float), stream);

    // layer 0: input projection, then persistent bidirectional recurrence
    gemm_proj<<<dim3(SEQ / 64, G4H / 64, 2), 256, 0, stream>>>(
        X, nullptr, nullptr, DIN, 0, Wih0f, b0f, Pf, Wih0b, b0b, Pb);
    lstm_layer<<<128, 256, 0, stream>>>(Pf, Pb, Whh0f, Whh0b, h0, c0, 0, hf0, hb0);

    // layer 1 (P buffers reused; layer-0 input y0 read straight from hist)
    gemm_proj<<<dim3(SEQ / 64, G4H / 64, 2), 256, 0, stream>>>(
        nullptr, hf0, hb0, 1024, 1, Wih1f, b1f, Pf, Wih1b, b1b, Pb);
    lstm_layer<<<128, 256, 0, stream>>>(Pf, Pb, Whh1f, Whh1b, h0, c0, 2, hf1, hb1);

    // tag head + Viterbi
    feats_kernel<<<SEQ / 4, 256, 0, stream>>>(hf1, hb1, Wtag, btag, feats);
    viterbi_scan<<<1, 64, 0, stream>>>(feats, trans, fvst, out, bestb);
    bp_kernel<<<(SEQ * KTAG) / 256, 256, 0, stream>>>(fvst, trans, bp);
    backtrace_kernel<<<1, 1024, 0, stream>>>(bp, bestb, out);
}